// Round 1
// baseline (110.412 us; speedup 1.0000x reference)
//
#include <hip/hip_runtime.h>
#include <hip/hip_bf16.h>

#define NMOV 32768
#define LW 15
#define DIM 256
#define NVOC 27
#define NR 405      // NVOC * LW distinct (letter, position) rows
#define GS 416      // padded row stride of G

__device__ __forceinline__ float b2f(unsigned short u) {
    return __uint_as_float(((unsigned int)u) << 16);
}

// ---------------------------------------------------------------------------
// Kernel 1: QT/KT/VT tables [405][256].  QT[c*15+l][d] = (le[c]+pos[l]) . Wq[d,:] + bq[d]
// 135 blocks = 27 letters x 5 groups of 3 positions; 256 threads (one per d).
// ---------------------------------------------------------------------------
__global__ __launch_bounds__(256) void qkv_tables(
    const float* __restrict__ le, const float* __restrict__ pos,
    const float* __restrict__ Wq, const float* __restrict__ bq,
    const float* __restrict__ Wk, const float* __restrict__ bk,
    const float* __restrict__ Wv, const float* __restrict__ bv,
    float* __restrict__ QT, float* __restrict__ KT,
    __hip_bfloat16* __restrict__ VT)
{
    const int c  = blockIdx.x / 5;
    const int lg = blockIdx.x % 5;
    const int d  = threadIdx.x;
    __shared__ float e[3][DIM];
    const float lv = le[c * DIM + d];
    #pragma unroll
    for (int k = 0; k < 3; ++k)
        e[k][d] = lv + pos[(lg * 3 + k) * DIM + d];
    __syncthreads();

    float aq[3], ak[3], av[3];
    #pragma unroll
    for (int k = 0; k < 3; ++k) { aq[k] = bq[d]; ak[k] = bk[d]; av[k] = bv[d]; }

    const float4* wq4 = (const float4*)(Wq + d * DIM);
    const float4* wk4 = (const float4*)(Wk + d * DIM);
    const float4* wv4 = (const float4*)(Wv + d * DIM);
    #pragma unroll 4
    for (int j4 = 0; j4 < DIM / 4; ++j4) {
        float4 q4 = wq4[j4], k4 = wk4[j4], v4 = wv4[j4];
        #pragma unroll
        for (int k = 0; k < 3; ++k) {
            float4 e4 = *(const float4*)&e[k][j4 * 4];
            aq[k] += e4.x * q4.x + e4.y * q4.y + e4.z * q4.z + e4.w * q4.w;
            ak[k] += e4.x * k4.x + e4.y * k4.y + e4.z * k4.z + e4.w * k4.w;
            av[k] += e4.x * v4.x + e4.y * v4.y + e4.z * v4.z + e4.w * v4.w;
        }
    }
    #pragma unroll
    for (int k = 0; k < 3; ++k) {
        int r = c * LW + lg * 3 + k;
        QT[r * DIM + d] = aq[k];
        KT[r * DIM + d] = ak[k];
        VT[r * DIM + d] = __float2bfloat16(av[k]);
    }
}

// ---------------------------------------------------------------------------
// Kernel 2: G[i][j] = QT[i,:] . KT[j,:]   (405x405, K=256), padded stride GS.
// 13x13 = 169 blocks, 32x32 tiles, BK=64, 256 threads (4 outputs each).
// ---------------------------------------------------------------------------
__global__ __launch_bounds__(256) void g_matrix(
    const float* __restrict__ QT, const float* __restrict__ KT,
    float* __restrict__ G)
{
    __shared__ float As[32 * 68];
    __shared__ float Bs[32 * 68];
    const int by = blockIdx.x / 13, bx = blockIdx.x % 13;
    const int i0 = by * 32, j0 = bx * 32;
    const int t = threadIdx.x;
    const int tx = t & 31, ty = t >> 5;     // ty in 0..7
    float acc[4] = {0.f, 0.f, 0.f, 0.f};

    for (int k0 = 0; k0 < DIM; k0 += 64) {
        #pragma unroll
        for (int s = 0; s < 8; ++s) {
            int lin = s * 256 + t;
            int r = lin >> 6, kk = lin & 63;
            int gi = i0 + r, gj = j0 + r;
            As[r * 68 + kk] = (gi < NR) ? QT[gi * DIM + k0 + kk] : 0.f;
            Bs[r * 68 + kk] = (gj < NR) ? KT[gj * DIM + k0 + kk] : 0.f;
        }
        __syncthreads();
        #pragma unroll
        for (int kk = 0; kk < 64; kk += 4) {
            float4 b4 = *(const float4*)&Bs[tx * 68 + kk];
            #pragma unroll
            for (int u = 0; u < 4; ++u) {
                float4 a4 = *(const float4*)&As[(ty * 4 + u) * 68 + kk];
                acc[u] += a4.x * b4.x + a4.y * b4.y + a4.z * b4.z + a4.w * b4.w;
            }
        }
        __syncthreads();
    }
    #pragma unroll
    for (int u = 0; u < 4; ++u) {
        int i = i0 + ty * 4 + u, j = j0 + tx;
        if (i < NR && j < NR) G[i * GS + j] = acc[u];
    }
}

// ---------------------------------------------------------------------------
// Kernel 3: per-move softmax colsum from G gathers + V combine + epilogue.
// 512 blocks x 256 threads, 64 moves per block.
// ---------------------------------------------------------------------------
__global__ __launch_bounds__(256) void moves_kernel(
    const int* __restrict__ words, const int* __restrict__ rowsI,
    const int* __restrict__ colsI, const int* __restrict__ dirsI,
    const int* __restrict__ scoresI,
    const float* __restrict__ G, const __hip_bfloat16* __restrict__ VT,
    const float* __restrict__ row_emb, const float* __restrict__ col_emb,
    const float* __restrict__ dir_emb, const float* __restrict__ score_emb,
    float* __restrict__ out)
{
    __shared__ int   rIdx[64 * LW];       // (letter,pos) row index per (move, pos)
    __shared__ float csum[4][64 * LW];    // partial column sums, 4 row-groups
    __shared__ int   meta[4][64];         // rows, cols, dirs, clamped scores
    const int base = blockIdx.x * 64;
    const int t = threadIdx.x;

    for (int idx = t; idx < 64 * LW; idx += 256) {
        int m = idx % LW;
        rIdx[idx] = words[base * LW + idx] * LW + m;
    }
    if (t < 64) {
        meta[0][t] = rowsI[base + t];
        meta[1][t] = colsI[base + t];
        meta[2][t] = dirsI[base + t];
        meta[3][t] = min(scoresI[base + t], 99);
    }
    __syncthreads();

    // -------- phase 1: 4 threads per move, rows l = grp, grp+4, grp+8, grp+12
    const int mv = t & 63, grp = t >> 6;
    int cm[LW];
    #pragma unroll
    for (int m = 0; m < LW; ++m) cm[m] = rIdx[mv * LW + m];
    float cs[LW];
    #pragma unroll
    for (int m = 0; m < LW; ++m) cs[m] = 0.f;

    #pragma unroll
    for (int k = 0; k < 4; ++k) {
        int l = grp + 4 * k;
        if (l < LW) {                      // uniform per wave (grp == wave id)
            int rl = rIdx[mv * LW + l];
            const float* grow = G + rl * GS;
            float s[LW];
            #pragma unroll
            for (int m = 0; m < LW; ++m) s[m] = grow[cm[m]];
            float mx = s[0];
            #pragma unroll
            for (int m = 1; m < LW; ++m) mx = fmaxf(mx, s[m]);
            float sum = 0.f;
            #pragma unroll
            for (int m = 0; m < LW; ++m) { s[m] = __expf(s[m] - mx); sum += s[m]; }
            float inv = 1.0f / sum;
            #pragma unroll
            for (int m = 0; m < LW; ++m) cs[m] += s[m] * inv;
        }
    }
    #pragma unroll
    for (int m = 0; m < LW; ++m) csum[grp][mv * LW + m] = cs[m];
    __syncthreads();
    for (int idx = t; idx < 64 * LW; idx += 256)
        csum[0][idx] = csum[0][idx] + csum[1][idx] + csum[2][idx] + csum[3][idx];
    __syncthreads();

    // -------- phase 2: 64 lanes over d (4 floats each), 4 moves in parallel
    const int iq = t >> 6;
    const int d0 = (t & 63) * 4;
    for (int it = 0; it < 16; ++it) {
        int i = it * 4 + iq;
        float wx = 0.f, wy = 0.f, wz = 0.f, ww = 0.f;
        #pragma unroll
        for (int m = 0; m < LW; ++m) {
            float c = csum[0][i * LW + m];
            int r = rIdx[i * LW + m];
            ushort4 vv = *(const ushort4*)((const unsigned short*)VT + r * DIM + d0);
            wx += c * b2f(vv.x); wy += c * b2f(vv.y);
            wz += c * b2f(vv.z); ww += c * b2f(vv.w);
        }
        int n = base + i;
        float4 re = *(const float4*)&row_emb[meta[0][i] * DIM + d0];
        float4 ce = *(const float4*)&col_emb[meta[1][i] * DIM + d0];
        float4 de = *(const float4*)&dir_emb[meta[2][i] * DIM + d0];
        float4 se = *(const float4*)&score_emb[meta[3][i] * DIM + d0];
        float4 res;
        res.x = 2.f * wx + re.x + ce.x + de.x + se.x;
        res.y = 2.f * wy + re.y + ce.y + de.y + se.y;
        res.z = 2.f * wz + re.z + ce.z + de.z + se.z;
        res.w = 2.f * ww + re.w + ce.w + de.w + se.w;
        *(float4*)&out[n * DIM + d0] = res;
    }
}

extern "C" void kernel_launch(void* const* d_in, const int* in_sizes, int n_in,
                              void* d_out, int out_size, void* d_ws, size_t ws_size,
                              hipStream_t stream)
{
    const int*   words      = (const int*)d_in[0];
    const int*   rowsI      = (const int*)d_in[1];
    const int*   colsI      = (const int*)d_in[2];
    const int*   dirsI      = (const int*)d_in[3];
    const int*   scoresI    = (const int*)d_in[4];
    const float* letter_emb = (const float*)d_in[5];
    const float* positional = (const float*)d_in[6];
    const float* Wq         = (const float*)d_in[7];
    const float* bq         = (const float*)d_in[8];
    const float* Wk         = (const float*)d_in[9];
    const float* bk         = (const float*)d_in[10];
    const float* Wv         = (const float*)d_in[11];
    const float* bv         = (const float*)d_in[12];
    const float* row_emb    = (const float*)d_in[13];
    const float* col_emb    = (const float*)d_in[14];
    const float* dir_emb    = (const float*)d_in[15];
    const float* score_emb  = (const float*)d_in[16];
    float* out = (float*)d_out;

    // workspace layout (floats): QT[405*256] | KT[405*256] | G[405*416] | VT bf16[405*256]
    float* QT = (float*)d_ws;
    float* KT = QT + NR * DIM;
    float* Gm = KT + NR * DIM;
    __hip_bfloat16* VT = (__hip_bfloat16*)(Gm + NR * GS);

    qkv_tables<<<135, 256, 0, stream>>>(letter_emb, positional, Wq, bq, Wk, bk,
                                        Wv, bv, QT, KT, VT);
    g_matrix<<<169, 256, 0, stream>>>(QT, KT, Gm);
    moves_kernel<<<512, 256, 0, stream>>>(words, rowsI, colsI, dirsI, scoresI,
                                          Gm, VT, row_emb, col_emb, dir_emb,
                                          score_emb, out);
}

// Round 2
// 80.827 us; speedup vs baseline: 1.3660x; 1.3660x over previous
//
#include <hip/hip_runtime.h>
#include <hip/hip_bf16.h>

#define NMOV 32768
#define LW 15
#define DIM 256
#define NVOC 27
#define NR 405      // NVOC * LW distinct (letter, position) rows
#define GS 416      // padded row stride of G
#define MPB 16      // moves per block in moves_kernel

__device__ __forceinline__ float b2f(unsigned short u) {
    return __uint_as_float(((unsigned int)u) << 16);
}

// ---------------------------------------------------------------------------
// Kernel 1: QT/KT/VT tables [405][256].  QT[c*15+l][d] = (le[c]+pos[l]) . Wq[d,:] + bq[d]
// 135 blocks = 27 letters x 5 groups of 3 positions; 256 threads (one per d).
// ---------------------------------------------------------------------------
__global__ __launch_bounds__(256) void qkv_tables(
    const float* __restrict__ le, const float* __restrict__ pos,
    const float* __restrict__ Wq, const float* __restrict__ bq,
    const float* __restrict__ Wk, const float* __restrict__ bk,
    const float* __restrict__ Wv, const float* __restrict__ bv,
    float* __restrict__ QT, float* __restrict__ KT,
    __hip_bfloat16* __restrict__ VT)
{
    const int c  = blockIdx.x / 5;
    const int lg = blockIdx.x % 5;
    const int d  = threadIdx.x;
    __shared__ float e[3][DIM];
    const float lv = le[c * DIM + d];
    #pragma unroll
    for (int k = 0; k < 3; ++k)
        e[k][d] = lv + pos[(lg * 3 + k) * DIM + d];
    __syncthreads();

    float aq[3], ak[3], av[3];
    #pragma unroll
    for (int k = 0; k < 3; ++k) { aq[k] = bq[d]; ak[k] = bk[d]; av[k] = bv[d]; }

    const float4* wq4 = (const float4*)(Wq + d * DIM);
    const float4* wk4 = (const float4*)(Wk + d * DIM);
    const float4* wv4 = (const float4*)(Wv + d * DIM);
    #pragma unroll 4
    for (int j4 = 0; j4 < DIM / 4; ++j4) {
        float4 q4 = wq4[j4], k4 = wk4[j4], v4 = wv4[j4];
        #pragma unroll
        for (int k = 0; k < 3; ++k) {
            float4 e4 = *(const float4*)&e[k][j4 * 4];
            aq[k] += e4.x * q4.x + e4.y * q4.y + e4.z * q4.z + e4.w * q4.w;
            ak[k] += e4.x * k4.x + e4.y * k4.y + e4.z * k4.z + e4.w * k4.w;
            av[k] += e4.x * v4.x + e4.y * v4.y + e4.z * v4.z + e4.w * v4.w;
        }
    }
    #pragma unroll
    for (int k = 0; k < 3; ++k) {
        int r = c * LW + lg * 3 + k;
        QT[r * DIM + d] = aq[k];
        KT[r * DIM + d] = ak[k];
        VT[r * DIM + d] = __float2bfloat16(av[k]);
    }
}

// ---------------------------------------------------------------------------
// Kernel 2: G[i][j] = QT[i,:] . KT[j,:]   (405x405, K=256), padded stride GS.
// 26x26 = 676 blocks, 16x16 tile, 256 threads, one output per thread.
// ---------------------------------------------------------------------------
__global__ __launch_bounds__(256) void g_matrix(
    const float* __restrict__ QT, const float* __restrict__ KT,
    float* __restrict__ G)
{
    __shared__ float As[16][DIM + 4];
    __shared__ float Bs[16][DIM + 4];
    const int by = blockIdx.x / 26, bx = blockIdx.x % 26;
    const int i0 = by * 16, j0 = bx * 16;
    const int t = threadIdx.x;

    #pragma unroll
    for (int s = 0; s < 4; ++s) {
        int lin = s * 256 + t;          // 0..1023 float4 slots
        int r = lin >> 6, c4 = lin & 63;
        int gi = i0 + r, gj = j0 + r;
        float4 qa = (gi < NR) ? *(const float4*)&QT[gi * DIM + c4 * 4]
                              : make_float4(0.f, 0.f, 0.f, 0.f);
        float4 kb = (gj < NR) ? *(const float4*)&KT[gj * DIM + c4 * 4]
                              : make_float4(0.f, 0.f, 0.f, 0.f);
        *(float4*)&As[r][c4 * 4] = qa;
        *(float4*)&Bs[r][c4 * 4] = kb;
    }
    __syncthreads();

    const int tj = t & 15, ti = t >> 4;
    float acc = 0.f;
    #pragma unroll 8
    for (int k = 0; k < DIM; k += 4) {
        float4 a = *(const float4*)&As[ti][k];
        float4 b = *(const float4*)&Bs[tj][k];
        acc += a.x * b.x + a.y * b.y + a.z * b.z + a.w * b.w;
    }
    int i = i0 + ti, j = j0 + tj;
    if (i < NR && j < NR) G[i * GS + j] = acc;
}

// ---------------------------------------------------------------------------
// Kernel 3: per-move softmax colsum from G gathers + V combine + epilogue.
// 2048 blocks x 256 threads, 16 moves per block.
// Phase 1: one thread per (move,row) -> 15 independent G gathers, softmax.
// Phase 1b: reduce att rows -> per-move column sums.
// Phase 2: d-parallel V combine + epilogue embeddings, float4 store.
// ---------------------------------------------------------------------------
__global__ __launch_bounds__(256) void moves_kernel(
    const int* __restrict__ words, const int* __restrict__ rowsI,
    const int* __restrict__ colsI, const int* __restrict__ dirsI,
    const int* __restrict__ scoresI,
    const float* __restrict__ G, const __hip_bfloat16* __restrict__ VT,
    const float* __restrict__ row_emb, const float* __restrict__ col_emb,
    const float* __restrict__ dir_emb, const float* __restrict__ score_emb,
    float* __restrict__ out)
{
    __shared__ int   rIdx[MPB * LW];         // 240 row indices
    __shared__ float tmp[MPB * LW][LW];      // per-(move,row) softmax weights
    __shared__ float csum[MPB][LW];          // per-move column sums
    __shared__ int   meta[4][MPB];           // rows, cols, dirs, scores
    const int base = blockIdx.x * MPB;
    const int t = threadIdx.x;

    if (t < MPB * LW)
        rIdx[t] = words[base * LW + t] * LW + (t % LW);
    if (t < 4 * MPB) {
        int sel = t >> 4, j = t & 15;
        const int* src = (sel == 0) ? rowsI : (sel == 1) ? colsI
                       : (sel == 2) ? dirsI : scoresI;
        int v = src[base + j];
        meta[sel][j] = (sel == 3) ? min(v, 99) : v;
    }
    __syncthreads();

    // -------- phase 1: thread t -> (move mv, row l)
    if (t < MPB * LW) {
        const int mv = t / LW;
        const int rl = rIdx[t];
        const float* grow = G + rl * GS;
        int cm[LW];
        #pragma unroll
        for (int m = 0; m < LW; ++m) cm[m] = rIdx[mv * LW + m];
        float s[LW];
        #pragma unroll
        for (int m = 0; m < LW; ++m) s[m] = grow[cm[m]];
        float mx = s[0];
        #pragma unroll
        for (int m = 1; m < LW; ++m) mx = fmaxf(mx, s[m]);
        float sum = 0.f;
        #pragma unroll
        for (int m = 0; m < LW; ++m) { s[m] = __expf(s[m] - mx); sum += s[m]; }
        float inv = 1.0f / sum;
        #pragma unroll
        for (int m = 0; m < LW; ++m) tmp[t][m] = s[m] * inv;
    }
    __syncthreads();

    // -------- phase 1b: thread t -> (move mv, column m), sum over rows l
    if (t < MPB * LW) {
        const int mv = t / LW, m = t % LW;
        float acc = 0.f;
        #pragma unroll
        for (int l = 0; l < LW; ++l) acc += tmp[mv * LW + l][m];
        csum[mv][m] = acc;
    }
    __syncthreads();

    // -------- phase 2: wave iq handles moves iq, 4+iq, 8+iq, 12+iq
    const int iq = t >> 6;
    const int d0 = (t & 63) * 4;
    #pragma unroll
    for (int it = 0; it < 4; ++it) {
        const int i = it * 4 + iq;
        float wx = 0.f, wy = 0.f, wz = 0.f, ww = 0.f;
        #pragma unroll
        for (int m = 0; m < LW; ++m) {
            float c = csum[i][m];
            int r = rIdx[i * LW + m];
            ushort4 vv = *(const ushort4*)((const unsigned short*)VT + r * DIM + d0);
            wx += c * b2f(vv.x); wy += c * b2f(vv.y);
            wz += c * b2f(vv.z); ww += c * b2f(vv.w);
        }
        const int n = base + i;
        float4 re = *(const float4*)&row_emb[meta[0][i] * DIM + d0];
        float4 ce = *(const float4*)&col_emb[meta[1][i] * DIM + d0];
        float4 de = *(const float4*)&dir_emb[meta[2][i] * DIM + d0];
        float4 se = *(const float4*)&score_emb[meta[3][i] * DIM + d0];
        float4 res;
        res.x = 2.f * wx + re.x + ce.x + de.x + se.x;
        res.y = 2.f * wy + re.y + ce.y + de.y + se.y;
        res.z = 2.f * wz + re.z + ce.z + de.z + se.z;
        res.w = 2.f * ww + re.w + ce.w + de.w + se.w;
        *(float4*)&out[n * DIM + d0] = res;
    }
}

extern "C" void kernel_launch(void* const* d_in, const int* in_sizes, int n_in,
                              void* d_out, int out_size, void* d_ws, size_t ws_size,
                              hipStream_t stream)
{
    const int*   words      = (const int*)d_in[0];
    const int*   rowsI      = (const int*)d_in[1];
    const int*   colsI      = (const int*)d_in[2];
    const int*   dirsI      = (const int*)d_in[3];
    const int*   scoresI    = (const int*)d_in[4];
    const float* letter_emb = (const float*)d_in[5];
    const float* positional = (const float*)d_in[6];
    const float* Wq         = (const float*)d_in[7];
    const float* bq         = (const float*)d_in[8];
    const float* Wk         = (const float*)d_in[9];
    const float* bk         = (const float*)d_in[10];
    const float* Wv         = (const float*)d_in[11];
    const float* bv         = (const float*)d_in[12];
    const float* row_emb    = (const float*)d_in[13];
    const float* col_emb    = (const float*)d_in[14];
    const float* dir_emb    = (const float*)d_in[15];
    const float* score_emb  = (const float*)d_in[16];
    float* out = (float*)d_out;

    // workspace layout (floats): QT[405*256] | KT[405*256] | G[405*416] | VT bf16[405*256]
    float* QT = (float*)d_ws;
    float* KT = QT + NR * DIM;
    float* Gm = KT + NR * DIM;
    __hip_bfloat16* VT = (__hip_bfloat16*)(Gm + NR * GS);

    qkv_tables<<<135, 256, 0, stream>>>(letter_emb, positional, Wq, bq, Wk, bk,
                                        Wv, bv, QT, KT, VT);
    g_matrix<<<676, 256, 0, stream>>>(QT, KT, Gm);
    moves_kernel<<<NMOV / MPB, 256, 0, stream>>>(words, rowsI, colsI, dirsI,
                                                 scoresI, Gm, VT, row_emb,
                                                 col_emb, dir_emb, score_emb,
                                                 out);
}

// Round 3
// 67.487 us; speedup vs baseline: 1.6360x; 1.1977x over previous
//
#include <hip/hip_runtime.h>
#include <hip/hip_bf16.h>

#define NMOV 32768
#define LW 15
#define DIM 256
#define NVOC 27
#define NR 405       // NVOC * LW distinct (letter, position) rows
#define GSH 408      // row stride of H in float2 units
#define MPB 8        // moves per block in moves_kernel

__device__ __forceinline__ float b2f(unsigned short u) {
    return __uint_as_float(((unsigned int)u) << 16);
}

// ---------------------------------------------------------------------------
// Kernel 1: QT/KT/VT tables [405][256], split by (letter, pos-group, matrix).
// 405 blocks = 27 x 5 x 3; 256 threads (one per output dim d).
// ---------------------------------------------------------------------------
__global__ __launch_bounds__(256) void qkv_tables(
    const float* __restrict__ le, const float* __restrict__ pos,
    const float* __restrict__ Wq, const float* __restrict__ bq,
    const float* __restrict__ Wk, const float* __restrict__ bk,
    const float* __restrict__ Wv, const float* __restrict__ bv,
    float* __restrict__ QT, float* __restrict__ KT,
    __hip_bfloat16* __restrict__ VT)
{
    const int b   = blockIdx.x;
    const int c   = b / 15;
    const int rem = b % 15;
    const int lg  = rem / 3;
    const int mat = rem % 3;
    const int d   = threadIdx.x;

    const float* W  = (mat == 0) ? Wq : (mat == 1) ? Wk : Wv;
    const float* bb = (mat == 0) ? bq : (mat == 1) ? bk : bv;

    __shared__ float e[3][DIM];
    const float lv = le[c * DIM + d];
    #pragma unroll
    for (int k = 0; k < 3; ++k)
        e[k][d] = lv + pos[(lg * 3 + k) * DIM + d];
    __syncthreads();

    float acc[3];
    const float bias = bb[d];
    #pragma unroll
    for (int k = 0; k < 3; ++k) acc[k] = bias;

    const float4* w4 = (const float4*)(W + d * DIM);
    #pragma unroll 8
    for (int j4 = 0; j4 < DIM / 4; ++j4) {
        float4 w = w4[j4];
        #pragma unroll
        for (int k = 0; k < 3; ++k) {
            float4 e4 = *(const float4*)&e[k][j4 * 4];
            acc[k] += e4.x * w.x + e4.y * w.y + e4.z * w.z + e4.w * w.w;
        }
    }
    #pragma unroll
    for (int k = 0; k < 3; ++k) {
        int r = c * LW + lg * 3 + k;
        if (mat == 0)      QT[r * DIM + d] = acc[k];
        else if (mat == 1) KT[r * DIM + d] = acc[k];
        else               VT[r * DIM + d] = __float2bfloat16(acc[k]);
    }
}

// ---------------------------------------------------------------------------
// Kernel 2: H[i][j] = { G[i][j], G[j][i] },  G[i][j] = QT[i,:].KT[j,:].
// Tile pairs (bi <= bj), 26*27/2 = 351 blocks, 16x16 tiles, BK=64.
// Each thread computes acc_ij = G[i0+ti][j0+tj] and acc_ji = G[j0+ti][i0+tj];
// transposes via LDS give the partner components.
// ---------------------------------------------------------------------------
__global__ __launch_bounds__(256) void h_matrix(
    const float* __restrict__ QT, const float* __restrict__ KT,
    float2* __restrict__ H)
{
    __shared__ float Qi[16][68], Ki[16][68], Qj[16][68], Kj[16][68];

    int rem = blockIdx.x, bi = 0, cnt = 26;
    while (rem >= cnt) { rem -= cnt; ++bi; --cnt; }
    const int bj = bi + rem;
    const int i0 = bi * 16, j0 = bj * 16;
    const int t = threadIdx.x;
    const int ti = t >> 4, tj = t & 15;

    float acc_ij = 0.f, acc_ji = 0.f;

    for (int k0 = 0; k0 < DIM; k0 += 64) {
        #pragma unroll
        for (int s = 0; s < 4; ++s) {
            int slot = s * 256 + t;          // 1024 float4 slots
            int tile = slot >> 8;            // 0:Qi 1:Ki 2:Qj 3:Kj
            int r    = (slot >> 4) & 15;
            int c4   = slot & 15;
            int grow = (tile < 2) ? (i0 + r) : (j0 + r);
            const float* src = (tile == 0 || tile == 2) ? QT : KT;
            float4 v = (grow < NR)
                ? *(const float4*)&src[grow * DIM + k0 + c4 * 4]
                : make_float4(0.f, 0.f, 0.f, 0.f);
            float* dst = (tile == 0) ? &Qi[r][c4 * 4]
                       : (tile == 1) ? &Ki[r][c4 * 4]
                       : (tile == 2) ? &Qj[r][c4 * 4] : &Kj[r][c4 * 4];
            *(float4*)dst = v;
        }
        __syncthreads();
        #pragma unroll 4
        for (int k = 0; k < 64; k += 4) {
            float4 qi = *(const float4*)&Qi[ti][k];
            float4 kj = *(const float4*)&Kj[tj][k];
            float4 qj = *(const float4*)&Qj[ti][k];
            float4 ki = *(const float4*)&Ki[tj][k];
            acc_ij += qi.x * kj.x + qi.y * kj.y + qi.z * kj.z + qi.w * kj.w;
            acc_ji += qj.x * ki.x + qj.y * ki.y + qj.z * ki.z + qj.w * ki.w;
        }
        __syncthreads();
    }

    // transpose both accs via LDS (reuse Qi/Ki)
    Qi[ti][tj] = acc_ij;
    Ki[ti][tj] = acc_ji;
    __syncthreads();
    const float t_ij = Qi[tj][ti];   // G[i0+tj][j0+ti]
    const float t_ji = Ki[tj][ti];   // G[j0+tj][i0+ti]

    const int i1 = i0 + ti, j1 = j0 + tj;
    if (i1 < NR && j1 < NR) H[i1 * GSH + j1] = make_float2(acc_ij, t_ji);
    const int i2 = j0 + ti, j2 = i0 + tj;
    if (i2 < NR && j2 < NR) H[i2 * GSH + j2] = make_float2(acc_ji, t_ij);
}

// ---------------------------------------------------------------------------
// Kernel 3: per-move softmax colsum via paired H gathers + V combine + epilogue.
// 4096 blocks x 256 threads, 8 moves per block (32 threads per move).
// Phase 1: 120 float2 pair-gathers per move fill the 15x15 S matrix in LDS.
// Phase 1b: row softmax (15 threads/move), then column sums.
// Phase 2: each wave handles 2 moves; d-parallel V combine + epilogue.
// ---------------------------------------------------------------------------
__global__ __launch_bounds__(256) void moves_kernel(
    const int* __restrict__ words, const int* __restrict__ rowsI,
    const int* __restrict__ colsI, const int* __restrict__ dirsI,
    const int* __restrict__ scoresI,
    const float2* __restrict__ H, const __hip_bfloat16* __restrict__ VT,
    const float* __restrict__ row_emb, const float* __restrict__ col_emb,
    const float* __restrict__ dir_emb, const float* __restrict__ score_emb,
    float* __restrict__ out)
{
    __shared__ float S[MPB][LW][17];     // 15x15 score matrix per move (padded)
    __shared__ int   rIdx[MPB * LW];     // 120 row indices
    __shared__ float csum[MPB][16];      // per-move column sums
    __shared__ int   meta[4][MPB];
    const int base = blockIdx.x * MPB;
    const int t = threadIdx.x;

    if (t < MPB * LW)
        rIdx[t] = words[base * LW + t] * LW + (t % LW);
    if (t < 4 * MPB) {
        int sel = t >> 3, j = t & 7;
        const int* src = (sel == 0) ? rowsI : (sel == 1) ? colsI
                       : (sel == 2) ? dirsI : scoresI;
        int v = src[base + j];
        meta[sel][j] = (sel == 3) ? min(v, 99) : v;
    }
    __syncthreads();

    // -------- phase 1: pair gathers. 32 threads per move, pairs p = j + 32k.
    const int mv = t >> 5, j = t & 31;
    #pragma unroll
    for (int k = 0; k < 4; ++k) {
        int p = j + 32 * k;
        if (p < 120) {
            int l = (int)((sqrtf(8.f * (float)p + 1.f) - 1.f) * 0.5f);
            if (l * (l + 1) / 2 > p) --l;
            int m = p - l * (l + 1) / 2;
            int rl = rIdx[mv * LW + l], rm = rIdx[mv * LW + m];
            float2 hv = H[rl * GSH + rm];
            S[mv][l][m] = hv.x;          // G[rl][rm] = S[l][m]
            S[mv][m][l] = hv.y;          // G[rm][rl] = S[m][l]
        }
    }
    __syncthreads();

    // -------- phase 1b: row softmax, weights written back into S
    if (j < LW) {
        float s[LW];
        #pragma unroll
        for (int m = 0; m < LW; ++m) s[m] = S[mv][j][m];
        float mx = s[0];
        #pragma unroll
        for (int m = 1; m < LW; ++m) mx = fmaxf(mx, s[m]);
        float sum = 0.f;
        #pragma unroll
        for (int m = 0; m < LW; ++m) { s[m] = __expf(s[m] - mx); sum += s[m]; }
        float inv = 1.0f / sum;
        #pragma unroll
        for (int m = 0; m < LW; ++m) S[mv][j][m] = s[m] * inv;
    }
    __syncthreads();

    // -------- column sums over rows
    if (j < LW) {
        float acc = 0.f;
        #pragma unroll
        for (int l = 0; l < LW; ++l) acc += S[mv][l][j];
        csum[mv][j] = acc;
    }
    __syncthreads();

    // -------- phase 2: wave w handles moves 2w, 2w+1
    const int wv = t >> 6;
    const int d0 = (t & 63) * 4;
    #pragma unroll
    for (int s2 = 0; s2 < 2; ++s2) {
        const int i = wv * 2 + s2;
        float wx = 0.f, wy = 0.f, wz = 0.f, ww = 0.f;
        #pragma unroll
        for (int m = 0; m < LW; ++m) {
            float c = csum[i][m];
            int r = rIdx[i * LW + m];
            ushort4 vv = *(const ushort4*)((const unsigned short*)VT + r * DIM + d0);
            wx += c * b2f(vv.x); wy += c * b2f(vv.y);
            wz += c * b2f(vv.z); ww += c * b2f(vv.w);
        }
        const int n = base + i;
        float4 re = *(const float4*)&row_emb[meta[0][i] * DIM + d0];
        float4 ce = *(const float4*)&col_emb[meta[1][i] * DIM + d0];
        float4 de = *(const float4*)&dir_emb[meta[2][i] * DIM + d0];
        float4 se = *(const float4*)&score_emb[meta[3][i] * DIM + d0];
        float4 res;
        res.x = 2.f * wx + re.x + ce.x + de.x + se.x;
        res.y = 2.f * wy + re.y + ce.y + de.y + se.y;
        res.z = 2.f * wz + re.z + ce.z + de.z + se.z;
        res.w = 2.f * ww + re.w + ce.w + de.w + se.w;
        *(float4*)&out[n * DIM + d0] = res;
    }
}

extern "C" void kernel_launch(void* const* d_in, const int* in_sizes, int n_in,
                              void* d_out, int out_size, void* d_ws, size_t ws_size,
                              hipStream_t stream)
{
    const int*   words      = (const int*)d_in[0];
    const int*   rowsI      = (const int*)d_in[1];
    const int*   colsI      = (const int*)d_in[2];
    const int*   dirsI      = (const int*)d_in[3];
    const int*   scoresI    = (const int*)d_in[4];
    const float* letter_emb = (const float*)d_in[5];
    const float* positional = (const float*)d_in[6];
    const float* Wq         = (const float*)d_in[7];
    const float* bq         = (const float*)d_in[8];
    const float* Wk         = (const float*)d_in[9];
    const float* bk         = (const float*)d_in[10];
    const float* Wv         = (const float*)d_in[11];
    const float* bv         = (const float*)d_in[12];
    const float* row_emb    = (const float*)d_in[13];
    const float* col_emb    = (const float*)d_in[14];
    const float* dir_emb    = (const float*)d_in[15];
    const float* score_emb  = (const float*)d_in[16];
    float* out = (float*)d_out;

    // workspace (bytes): QT f32[405*256] | KT f32[405*256] | H f2[405*408] | VT bf16[405*256]
    float*  QT = (float*)d_ws;
    float*  KT = QT + NR * DIM;
    float2* Hm = (float2*)(KT + NR * DIM);
    __hip_bfloat16* VT = (__hip_bfloat16*)((char*)Hm + (size_t)NR * GSH * sizeof(float2));

    qkv_tables<<<405, 256, 0, stream>>>(letter_emb, positional, Wq, bq, Wk, bk,
                                        Wv, bv, QT, KT, VT);
    h_matrix<<<351, 256, 0, stream>>>(QT, KT, Hm);
    moves_kernel<<<NMOV / MPB, 256, 0, stream>>>(words, rowsI, colsI, dirsI,
                                                 scoresI, Hm, VT, row_emb,
                                                 col_emb, dir_emb, score_emb,
                                                 out);
}